// Round 1
// baseline (43047.510 us; speedup 1.0000x reference)
//
#include <hip/hip_runtime.h>
#include <hip/hip_bf16.h>
#include <hip/hip_cooperative_groups.h>

namespace cg = cooperative_groups;

using bf16x8 = __attribute__((ext_vector_type(8))) __bf16;
using f32x4  = __attribute__((ext_vector_type(4))) float;

__device__ __forceinline__ ushort f2bf(float f) {
  uint u = __builtin_bit_cast(uint, f);
  u += 0x7FFFu + ((u >> 16) & 1u);   // RNE
  return (ushort)(u >> 16);
}
__device__ __forceinline__ float sigm(float x) { return 1.0f / (1.0f + __expf(-x)); }
__device__ __forceinline__ float tanhfast(float x) { return 1.0f - 2.0f / (__expf(2.0f * x) + 1.0f); }

// ---------- prep kernels ----------
__global__ void k_cvt(const float* __restrict__ s, ushort* __restrict__ d, int n4) {
  int i = blockIdx.x * blockDim.x + threadIdx.x;
  if (i < n4) {
    float4 v = reinterpret_cast<const float4*>(s)[i];
    ushort4 o;
    o.x = f2bf(v.x); o.y = f2bf(v.y); o.z = f2bf(v.z); o.w = f2bf(v.w);
    reinterpret_cast<ushort4*>(d)[i] = o;
  }
}

__global__ void k_bias(const float* __restrict__ a, const float* __restrict__ b,
                       float* __restrict__ o, int n) {
  int i = blockIdx.x * blockDim.x + threadIdx.x;
  if (i < n) o[i] = a[i] + b[i];
}

// in [B=64][T][K] f32 -> out [T][64][K] bf16
__global__ void k_xpose(const float* __restrict__ in, ushort* __restrict__ out, int T, int K) {
  int row = blockIdx.x;            // b*T + t
  int b = row / T, t = row - b * T;
  const float4* s = reinterpret_cast<const float4*>(in + (size_t)row * K);
  ushort4* d = reinterpret_cast<ushort4*>(out + ((size_t)t * 64 + b) * K);
  int K4 = K >> 2;
  for (int k = threadIdx.x; k < K4; k += blockDim.x) {
    float4 v = s[k];
    ushort4 o;
    o.x = f2bf(v.x); o.y = f2bf(v.y); o.z = f2bf(v.z); o.w = f2bf(v.w);
    d[k] = o;
  }
}

// ---------- persistent LSTM recurrence (cooperative) ----------
// block n owns hidden units [4n,4n+4) -> 16 gate columns {g*1024 + 4n + u}.
// LDS: Wl[16 cols][K1+1024] bf16 (XOR-swizzled), then gbuf[4][16][17] f32.
template<int K1, bool STORE_HS>
__global__ __launch_bounds__(256, 1) void k_lstm(
    const ushort* __restrict__ xseq,   // [T][64][K1] bf16
    const ushort* __restrict__ Wih,    // [4096][K1] bf16
    const ushort* __restrict__ Whh,    // [4096][1024] bf16
    const float*  __restrict__ bias,   // [4096] (bih+bhh)
    ushort* hbuf,                      // [2][64][1024] bf16 (double buffer)
    float*  cbuf,                      // [64][1024] f32
    ushort* hs_out,                    // [T][64][1024] bf16 (decoder only)
    int T)
{
  constexpr int KT = K1 + 1024;
  extern __shared__ char smem[];
  float* gbuf = reinterpret_cast<float*>(smem + (size_t)16 * KT * 2);

  const int tid = threadIdx.x;
  const int lane = tid & 63;
  const int w = tid >> 6;
  const int n0 = blockIdx.x * 4;
  const int ccol = lane & 15;          // block-local gate column 0..15
  const int kg = lane >> 4;            // k-group 0..3

  // stage the 16 gathered weight rows into LDS (once; stationary over T steps)
  const int kch = KT / 8;
  for (int ch = tid; ch < 16 * kch; ch += 256) {
    int c = ch / kch;
    int k = (ch - c * kch) * 8;
    int grow = (c >> 2) * 1024 + n0 + (c & 3);
    const ushort* src = (k < K1) ? (Wih + (size_t)grow * K1 + k)
                                 : (Whh + (size_t)grow * 1024 + (k - K1));
    uint4 v = *reinterpret_cast<const uint4*>(src);
    uint off = ((uint)(c * KT + k) * 2u) ^ (((uint)(c & 7)) << 4);
    *reinterpret_cast<uint4*>(smem + off) = v;
  }
  const float bc = bias[(ccol >> 2) * 1024 + n0 + (ccol & 3)];
  __syncthreads();

  cg::grid_group gg = cg::this_grid();

  const int arow = w * 16 + (lane & 15);      // batch row for A fragments
  const uint crow = (uint)(ccol * KT) * 2u;
  const uint cx = ((uint)(ccol & 7)) << 4;
  float* gb = gbuf + w * (16 * 17);

  for (int t = 0; t < T; ++t) {
    const ushort* a1 = xseq + (size_t)t * 64 * K1 + (size_t)arow * K1;
    const ushort* a2 = hbuf + (size_t)(t & 1) * 65536 + (size_t)arow * 1024;

    f32x4 acc[4];
    #pragma unroll
    for (int j = 0; j < 4; ++j) acc[j] = (f32x4){0.f, 0.f, 0.f, 0.f};

    // x-part: K1 (no dependence on h)
    for (int kk8 = 0; kk8 < K1 / 32; kk8 += 8) {
      #pragma unroll
      for (int j = 0; j < 8; ++j) {
        int k0 = (kk8 + j) * 32 + kg * 8;
        bf16x8 a = *reinterpret_cast<const bf16x8*>(a1 + k0);
        uint off = (crow + (uint)k0 * 2u) ^ cx;
        bf16x8 b = *reinterpret_cast<const bf16x8*>(smem + off);
        acc[j & 3] = __builtin_amdgcn_mfma_f32_16x16x32_bf16(a, b, acc[j & 3], 0, 0, 0);
      }
    }
    // h-part: 1024
    for (int kk8 = 0; kk8 < 32; kk8 += 8) {
      #pragma unroll
      for (int j = 0; j < 8; ++j) {
        int k0 = (kk8 + j) * 32 + kg * 8;
        bf16x8 a = *reinterpret_cast<const bf16x8*>(a2 + k0);
        uint off = (crow + (uint)(K1 + k0) * 2u) ^ cx;
        bf16x8 b = *reinterpret_cast<const bf16x8*>(smem + off);
        acc[j & 3] = __builtin_amdgcn_mfma_f32_16x16x32_bf16(a, b, acc[j & 3], 0, 0, 0);
      }
    }

    f32x4 fa = acc[0] + acc[1] + acc[2] + acc[3];
    #pragma unroll
    for (int r = 0; r < 4; ++r)
      gb[(kg * 4 + r) * 17 + ccol] = fa[r] + bc;   // C/D: row=(l>>4)*4+r, col=l&15
    __syncthreads();

    // gate update: lane -> (batch row = lane&15, unit = kg)
    {
      int row = lane & 15;
      int gu = n0 + kg;
      int grow = w * 16 + row;
      float gi = gb[row * 17 + kg];
      float gf = gb[row * 17 + 4 + kg];
      float gG = gb[row * 17 + 8 + kg];
      float go = gb[row * 17 + 12 + kg];
      float ii = sigm(gi), ff = sigm(gf), g2 = tanhfast(gG), oo = sigm(go);
      size_t ci = (size_t)grow * 1024 + gu;
      float cn = ff * cbuf[ci] + ii * g2;
      float hn = oo * tanhfast(cn);
      cbuf[ci] = cn;
      ushort hv = f2bf(hn);
      hbuf[(size_t)((t + 1) & 1) * 65536 + ci] = hv;
      if (STORE_HS) hs_out[(size_t)t * 65536 + ci] = hv;
    }
    gg.sync();
  }
}

// ---------- MLP GEMM: C = relu?(A[M][K] @ W[N][K]^T + bias) ----------
template<bool RELU, bool REMAP>
__global__ __launch_bounds__(256) void k_gemm(
    const ushort* __restrict__ A, const ushort* __restrict__ W,
    const float* __restrict__ bias,
    ushort* __restrict__ obf, float* __restrict__ of32,
    int N, int K)
{
  const int tid = threadIdx.x, lane = tid & 63, w = tid >> 6;
  const int kg = lane >> 4, lr = lane & 15;
  const int r0 = blockIdx.x * 64 + w * 16;
  const int n0 = blockIdx.y * 64;
  f32x4 acc[4];
  #pragma unroll
  for (int j = 0; j < 4; ++j) acc[j] = (f32x4){0.f, 0.f, 0.f, 0.f};
  const ushort* ap = A + (size_t)(r0 + lr) * K;
  const ushort* wp = W + (size_t)(n0 + lr) * K;
  #pragma unroll 4
  for (int kk = 0; kk < K / 32; ++kk) {
    int k0 = kk * 32 + kg * 8;
    bf16x8 a = *reinterpret_cast<const bf16x8*>(ap + k0);
    #pragma unroll
    for (int ct = 0; ct < 4; ++ct) {
      bf16x8 b = *reinterpret_cast<const bf16x8*>(wp + (size_t)(ct * 16) * K + k0);
      acc[ct] = __builtin_amdgcn_mfma_f32_16x16x32_bf16(a, b, acc[ct], 0, 0, 0);
    }
  }
  #pragma unroll
  for (int ct = 0; ct < 4; ++ct) {
    int col = n0 + ct * 16 + lr;
    float bv = bias[col];
    #pragma unroll
    for (int r = 0; r < 4; ++r) {
      int row = r0 + kg * 4 + r;             // row = t*64 + b
      float v = acc[ct][r] + bv;
      if (RELU) v = fmaxf(v, 0.f);
      if (REMAP) {
        of32[((size_t)(row & 63) * 512 + (row >> 6)) * 256 + col] = v;  // out[b][t][col]
      } else {
        obf[(size_t)row * N + col] = f2bf(v);
      }
    }
  }
}

// ---------- launch ----------
extern "C" void kernel_launch(void* const* d_in, const int* in_sizes, int n_in,
                              void* d_out, int out_size, void* d_ws, size_t ws_size,
                              hipStream_t stream) {
  const float* in_seq  = (const float*)d_in[0];
  const float* tgt_seq = (const float*)d_in[1];
  const float* eWih = (const float*)d_in[2];
  const float* eWhh = (const float*)d_in[3];
  const float* eBih = (const float*)d_in[4];
  const float* eBhh = (const float*)d_in[5];
  const float* dWih = (const float*)d_in[6];
  const float* dWhh = (const float*)d_in[7];
  const float* dBih = (const float*)d_in[8];
  const float* dBhh = (const float*)d_in[9];
  const float* W1 = (const float*)d_in[10];
  const float* b1 = (const float*)d_in[11];
  const float* W2 = (const float*)d_in[12];
  const float* b2 = (const float*)d_in[13];
  const float* W3 = (const float*)d_in[14];
  const float* b3 = (const float*)d_in[15];

  char* ws = (char*)d_ws;
  size_t off = 0;
  auto alloc = [&](size_t bytes) { char* p = ws + off; off += (bytes + 255) & ~(size_t)255; return p; };
  ushort* eWih_b = (ushort*)alloc((size_t)4096 * 256 * 2);
  ushort* eWhh_b = (ushort*)alloc((size_t)4096 * 1024 * 2);
  ushort* dWih_b = (ushort*)alloc((size_t)4096 * 1024 * 2);
  ushort* dWhh_b = (ushort*)alloc((size_t)4096 * 1024 * 2);
  ushort* W1_b   = (ushort*)alloc((size_t)256 * 1024 * 2);
  ushort* W2_b   = (ushort*)alloc((size_t)128 * 256 * 2);
  ushort* W3_b   = (ushort*)alloc((size_t)256 * 128 * 2);
  float*  be     = (float*)alloc(4096 * 4);
  float*  bd     = (float*)alloc(4096 * 4);
  ushort* xe     = (ushort*)alloc((size_t)512 * 64 * 256 * 2);
  ushort* xd     = (ushort*)alloc((size_t)512 * 64 * 1024 * 2);
  ushort* hb     = (ushort*)alloc((size_t)2 * 64 * 1024 * 2);
  float*  cb     = (float*)alloc((size_t)64 * 1024 * 4);
  ushort* dhs    = (ushort*)alloc((size_t)512 * 64 * 1024 * 2);
  ushort* x1     = (ushort*)alloc((size_t)32768 * 256 * 2);
  ushort* x2     = (ushort*)alloc((size_t)32768 * 128 * 2);
  if (ws_size < off) return;  // constant branch per run; avoids corrupting memory

  auto cvt = [&](const float* s, ushort* d, size_t n) {
    int n4 = (int)(n / 4);
    k_cvt<<<(n4 + 255) / 256, 256, 0, stream>>>(s, d, n4);
  };
  cvt(eWih, eWih_b, (size_t)4096 * 256);
  cvt(eWhh, eWhh_b, (size_t)4096 * 1024);
  cvt(dWih, dWih_b, (size_t)4096 * 1024);
  cvt(dWhh, dWhh_b, (size_t)4096 * 1024);
  cvt(W1, W1_b, (size_t)256 * 1024);
  cvt(W2, W2_b, (size_t)128 * 256);
  cvt(W3, W3_b, (size_t)256 * 128);
  k_bias<<<16, 256, 0, stream>>>(eBih, eBhh, be, 4096);
  k_bias<<<16, 256, 0, stream>>>(dBih, dBhh, bd, 4096);
  k_xpose<<<64 * 512, 256, 0, stream>>>(in_seq, xe, 512, 256);
  k_xpose<<<64 * 512, 256, 0, stream>>>(tgt_seq, xd, 512, 1024);
  hipMemsetAsync(hb, 0, (size_t)2 * 64 * 1024 * 2, stream);
  hipMemsetAsync(cb, 0, (size_t)64 * 1024 * 4, stream);

  const unsigned ldsE = 16 * (256 + 1024) * 2 + 4 * 16 * 17 * 4;   // 45312
  const unsigned ldsD = 16 * (1024 + 1024) * 2 + 4 * 16 * 17 * 4;  // 69888
  hipFuncSetAttribute((const void*)k_lstm<256, false>, hipFuncAttributeMaxDynamicSharedMemorySize, (int)ldsE);
  hipFuncSetAttribute((const void*)k_lstm<1024, true>, hipFuncAttributeMaxDynamicSharedMemorySize, (int)ldsD);

  int T = 512;
  {
    const ushort* xp = xe; const ushort* wi = eWih_b; const ushort* wh = eWhh_b; const float* bp = be;
    ushort* hbp = hb; float* cbp = cb; ushort* hsp = nullptr;
    void* args[] = {&xp, &wi, &wh, &bp, &hbp, &cbp, &hsp, &T};
    hipLaunchCooperativeKernel((const void*)k_lstm<256, false>, dim3(256), dim3(256), args, ldsE, stream);
  }
  {
    const ushort* xp = xd; const ushort* wi = dWih_b; const ushort* wh = dWhh_b; const float* bp = bd;
    ushort* hbp = hb; float* cbp = cb; ushort* hsp = dhs;
    void* args[] = {&xp, &wi, &wh, &bp, &hbp, &cbp, &hsp, &T};
    hipLaunchCooperativeKernel((const void*)k_lstm<1024, true>, dim3(256), dim3(256), args, ldsD, stream);
  }

  k_gemm<true,  false><<<dim3(512, 4), 256, 0, stream>>>(dhs, W1_b, b1, x1, nullptr, 256, 1024);
  k_gemm<true,  false><<<dim3(512, 2), 256, 0, stream>>>(x1,  W2_b, b2, x2, nullptr, 128, 256);
  k_gemm<false, true ><<<dim3(512, 4), 256, 0, stream>>>(x2,  W3_b, b3, nullptr, (float*)d_out, 256, 128);
}

// Round 2
// 18269.084 us; speedup vs baseline: 2.3563x; 2.3563x over previous
//
#include <hip/hip_runtime.h>
#include <hip/hip_bf16.h>

using bf16x8 = __attribute__((ext_vector_type(8))) __bf16;
using f32x4  = __attribute__((ext_vector_type(4))) float;

__device__ __forceinline__ ushort f2bf(float f) {
  uint u = __builtin_bit_cast(uint, f);
  u += 0x7FFFu + ((u >> 16) & 1u);   // RNE
  return (ushort)(u >> 16);
}
__device__ __forceinline__ float sigm(float x) { return 1.0f / (1.0f + __expf(-x)); }
__device__ __forceinline__ float tanhfast(float x) { return 1.0f - 2.0f / (__expf(2.0f * x) + 1.0f); }

// ---------- prep kernels ----------
__global__ void k_cvt(const float* __restrict__ s, ushort* __restrict__ d, int n4) {
  int i = blockIdx.x * blockDim.x + threadIdx.x;
  if (i < n4) {
    float4 v = reinterpret_cast<const float4*>(s)[i];
    ushort4 o;
    o.x = f2bf(v.x); o.y = f2bf(v.y); o.z = f2bf(v.z); o.w = f2bf(v.w);
    reinterpret_cast<ushort4*>(d)[i] = o;
  }
}

__global__ void k_bias(const float* __restrict__ a, const float* __restrict__ b,
                       float* __restrict__ o, int n) {
  int i = blockIdx.x * blockDim.x + threadIdx.x;
  if (i < n) o[i] = a[i] + b[i];
}

// in [B=64][T][K] f32 -> out [T][64][K] bf16
__global__ void k_xpose(const float* __restrict__ in, ushort* __restrict__ out, int T, int K) {
  int row = blockIdx.x;            // b*T + t
  int b = row / T, t = row - b * T;
  const float4* s = reinterpret_cast<const float4*>(in + (size_t)row * K);
  ushort4* d = reinterpret_cast<ushort4*>(out + ((size_t)t * 64 + b) * K);
  int K4 = K >> 2;
  for (int k = threadIdx.x; k < K4; k += blockDim.x) {
    float4 v = s[k];
    ushort4 o;
    o.x = f2bf(v.x); o.y = f2bf(v.y); o.z = f2bf(v.z); o.w = f2bf(v.w);
    d[k] = o;
  }
}

// ---------- persistent LSTM recurrence ----------
// block n owns hidden units [4n,4n+4) -> 16 gate columns {g*1024 + 4n + u}.
// Cross-block h exchange: write-through stores (sc0 sc1) + flag array barrier
// (relaxed agent atomics) + buffer_inv sc1 acquire. c lives in a register.
// LDS: W[16 cols][K1+1024] bf16 (XOR-swizzled) | gbuf[4][16][17] f32 | hpack[64][4] ushort
template<int K1, bool STORE_HS>
__global__ __launch_bounds__(256, 1) void k_lstm(
    const ushort* __restrict__ xseq,   // [T][64][K1] bf16
    const ushort* __restrict__ Wih,    // [4096][K1] bf16
    const ushort* __restrict__ Whh,    // [4096][1024] bf16
    const float*  __restrict__ bias,   // [4096] (bih+bhh)
    ushort* hbuf,                      // [2][64][1024] bf16 (double buffer; NOT restrict)
    float*  cbuf,                      // [64][1024] f32 (carry across enc->dec)
    ushort* hs_out,                    // [T][64][1024] bf16 (decoder only)
    uint*   flags,                     // [256] step completion flags (zeroed)
    int T)
{
  constexpr int KT = K1 + 1024;
  extern __shared__ char smem[];
  float*  gbuf  = reinterpret_cast<float*>(smem + (size_t)16 * KT * 2);
  ushort* hpack = reinterpret_cast<ushort*>(smem + (size_t)16 * KT * 2 + 4 * 16 * 17 * 4);

  const int tid = threadIdx.x;
  const int lane = tid & 63;
  const int w = tid >> 6;
  const int n0 = blockIdx.x * 4;
  const int ccol = lane & 15;          // block-local gate column 0..15
  const int kg = lane >> 4;            // k-group 0..3

  // stage the 16 gathered weight rows into LDS (once; stationary over T steps)
  const int kch = KT / 8;
  for (int ch = tid; ch < 16 * kch; ch += 256) {
    int c = ch / kch;
    int k = (ch - c * kch) * 8;
    int grow = (c >> 2) * 1024 + n0 + (c & 3);
    const ushort* src = (k < K1) ? (Wih + (size_t)grow * K1 + k)
                                 : (Whh + (size_t)grow * 1024 + (k - K1));
    uint4 v = *reinterpret_cast<const uint4*>(src);
    uint off = ((uint)(c * KT + k) * 2u) ^ (((uint)(c & 7)) << 4);
    *reinterpret_cast<uint4*>(smem + off) = v;
  }
  const float bc = bias[(ccol >> 2) * 1024 + n0 + (ccol & 3)];
  __syncthreads();

  const int arow = w * 16 + (lane & 15);      // batch row for A fragments
  const uint crow = (uint)(ccol * KT) * 2u;
  const uint cx = ((uint)(ccol & 7)) << 4;
  float* gb = gbuf + w * (16 * 17);

  // per-thread cell state: this thread owns (row=grow, unit=gu)
  const int grow = w * 16 + (lane & 15);
  const int gu = n0 + kg;
  const size_t ci = (size_t)grow * 1024 + gu;
  float creg = cbuf[ci];

  for (int t = 0; t < T; ++t) {
    const ushort* a1 = xseq + (size_t)t * 64 * K1 + (size_t)arow * K1;
    const ushort* a2 = hbuf + (size_t)(t & 1) * 65536 + (size_t)arow * 1024;

    f32x4 acc[4];
    #pragma unroll
    for (int j = 0; j < 4; ++j) acc[j] = (f32x4){0.f, 0.f, 0.f, 0.f};

    // x-part: no dependence on h(t) -> compute BEFORE the barrier wait
    for (int kk8 = 0; kk8 < K1 / 32; kk8 += 8) {
      #pragma unroll
      for (int j = 0; j < 8; ++j) {
        int k0 = (kk8 + j) * 32 + kg * 8;
        bf16x8 a = *reinterpret_cast<const bf16x8*>(a1 + k0);
        uint off = (crow + (uint)k0 * 2u) ^ cx;
        bf16x8 b = *reinterpret_cast<const bf16x8*>(smem + off);
        acc[j & 3] = __builtin_amdgcn_mfma_f32_16x16x32_bf16(a, b, acc[j & 3], 0, 0, 0);
      }
    }

    // flat barrier: wait until all 256 blocks have published h(t)
    if (t > 0 && w == 0) {
      const uint tgt = (uint)t;
      for (;;) {
        uint a0 = __hip_atomic_load(flags + lane,       __ATOMIC_RELAXED, __HIP_MEMORY_SCOPE_AGENT);
        uint b0 = __hip_atomic_load(flags + lane + 64,  __ATOMIC_RELAXED, __HIP_MEMORY_SCOPE_AGENT);
        uint c0 = __hip_atomic_load(flags + lane + 128, __ATOMIC_RELAXED, __HIP_MEMORY_SCOPE_AGENT);
        uint d0 = __hip_atomic_load(flags + lane + 192, __ATOMIC_RELAXED, __HIP_MEMORY_SCOPE_AGENT);
        if (__all(a0 >= tgt && b0 >= tgt && c0 >= tgt && d0 >= tgt)) break;
        __builtin_amdgcn_s_sleep(1);
      }
    }
    __syncthreads();
    // acquire: drop (clean) L2 lines so h(t) is re-fetched from IC. h stores
    // were write-through, so nothing dirty is lost; x is clean read-only.
    asm volatile("buffer_inv sc1" ::: "memory");

    // h-part: plain cached loads (fresh after inv; L2-shared within the XCD)
    for (int kk8 = 0; kk8 < 32; kk8 += 8) {
      #pragma unroll
      for (int j = 0; j < 8; ++j) {
        int k0 = (kk8 + j) * 32 + kg * 8;
        bf16x8 a = *reinterpret_cast<const bf16x8*>(a2 + k0);
        uint off = (crow + (uint)(K1 + k0) * 2u) ^ cx;
        bf16x8 b = *reinterpret_cast<const bf16x8*>(smem + off);
        acc[j & 3] = __builtin_amdgcn_mfma_f32_16x16x32_bf16(a, b, acc[j & 3], 0, 0, 0);
      }
    }

    f32x4 fa = acc[0] + acc[1] + acc[2] + acc[3];
    #pragma unroll
    for (int r = 0; r < 4; ++r)
      gb[(kg * 4 + r) * 17 + ccol] = fa[r] + bc;   // C/D: row=(l>>4)*4+r, col=l&15
    __syncthreads();

    // gate update: lane -> (batch row = lane&15, unit = kg); c in register
    {
      int row = lane & 15;
      float gi = gb[row * 17 + kg];
      float gf = gb[row * 17 + 4 + kg];
      float gG = gb[row * 17 + 8 + kg];
      float go = gb[row * 17 + 12 + kg];
      float ii = sigm(gi), ff = sigm(gf), g2 = tanhfast(gG), oo = sigm(go);
      float cn = ff * creg + ii * g2;
      float hn = oo * tanhfast(cn);
      creg = cn;
      hpack[grow * 4 + kg] = f2bf(hn);
    }
    __syncthreads();

    // publish h(t+1): wave 0, lane b stores 4 units (8 B) write-through
    if (w == 0) {
      uint2 hv2 = *reinterpret_cast<const uint2*>(hpack + lane * 4);
      ushort* dst = hbuf + (size_t)((t + 1) & 1) * 65536 + (size_t)lane * 1024 + n0;
      asm volatile("global_store_dwordx2 %0, %1, off sc0 sc1" :: "v"(dst), "v"(hv2) : "memory");
      if (STORE_HS)
        *reinterpret_cast<uint2*>(hs_out + (size_t)t * 65536 + (size_t)lane * 1024 + n0) = hv2;
      asm volatile("s_waitcnt vmcnt(0)" ::: "memory");
      if (lane == 0)
        __hip_atomic_store(flags + blockIdx.x, (uint)(t + 1), __ATOMIC_RELAXED, __HIP_MEMORY_SCOPE_AGENT);
    }
  }
  cbuf[ci] = creg;   // carry cell state to the decoder kernel
}

// ---------- MLP GEMM: C = relu?(A[M][K] @ W[N][K]^T + bias) ----------
template<bool RELU, bool REMAP>
__global__ __launch_bounds__(256) void k_gemm(
    const ushort* __restrict__ A, const ushort* __restrict__ W,
    const float* __restrict__ bias,
    ushort* __restrict__ obf, float* __restrict__ of32,
    int N, int K)
{
  const int tid = threadIdx.x, lane = tid & 63, w = tid >> 6;
  const int kg = lane >> 4, lr = lane & 15;
  const int r0 = blockIdx.x * 64 + w * 16;
  const int n0 = blockIdx.y * 64;
  f32x4 acc[4];
  #pragma unroll
  for (int j = 0; j < 4; ++j) acc[j] = (f32x4){0.f, 0.f, 0.f, 0.f};
  const ushort* ap = A + (size_t)(r0 + lr) * K;
  const ushort* wp = W + (size_t)(n0 + lr) * K;
  #pragma unroll 4
  for (int kk = 0; kk < K / 32; ++kk) {
    int k0 = kk * 32 + kg * 8;
    bf16x8 a = *reinterpret_cast<const bf16x8*>(ap + k0);
    #pragma unroll
    for (int ct = 0; ct < 4; ++ct) {
      bf16x8 b = *reinterpret_cast<const bf16x8*>(wp + (size_t)(ct * 16) * K + k0);
      acc[ct] = __builtin_amdgcn_mfma_f32_16x16x32_bf16(a, b, acc[ct], 0, 0, 0);
    }
  }
  #pragma unroll
  for (int ct = 0; ct < 4; ++ct) {
    int col = n0 + ct * 16 + lr;
    float bv = bias[col];
    #pragma unroll
    for (int r = 0; r < 4; ++r) {
      int row = r0 + kg * 4 + r;             // row = t*64 + b
      float v = acc[ct][r] + bv;
      if (RELU) v = fmaxf(v, 0.f);
      if (REMAP) {
        of32[((size_t)(row & 63) * 512 + (row >> 6)) * 256 + col] = v;  // out[b][t][col]
      } else {
        obf[(size_t)row * N + col] = f2bf(v);
      }
    }
  }
}

// ---------- launch ----------
extern "C" void kernel_launch(void* const* d_in, const int* in_sizes, int n_in,
                              void* d_out, int out_size, void* d_ws, size_t ws_size,
                              hipStream_t stream) {
  const float* in_seq  = (const float*)d_in[0];
  const float* tgt_seq = (const float*)d_in[1];
  const float* eWih = (const float*)d_in[2];
  const float* eWhh = (const float*)d_in[3];
  const float* eBih = (const float*)d_in[4];
  const float* eBhh = (const float*)d_in[5];
  const float* dWih = (const float*)d_in[6];
  const float* dWhh = (const float*)d_in[7];
  const float* dBih = (const float*)d_in[8];
  const float* dBhh = (const float*)d_in[9];
  const float* W1 = (const float*)d_in[10];
  const float* b1 = (const float*)d_in[11];
  const float* W2 = (const float*)d_in[12];
  const float* b2 = (const float*)d_in[13];
  const float* W3 = (const float*)d_in[14];
  const float* b3 = (const float*)d_in[15];

  char* ws = (char*)d_ws;
  size_t off = 0;
  auto alloc = [&](size_t bytes) { char* p = ws + off; off += (bytes + 255) & ~(size_t)255; return p; };
  ushort* eWih_b = (ushort*)alloc((size_t)4096 * 256 * 2);
  ushort* eWhh_b = (ushort*)alloc((size_t)4096 * 1024 * 2);
  ushort* dWih_b = (ushort*)alloc((size_t)4096 * 1024 * 2);
  ushort* dWhh_b = (ushort*)alloc((size_t)4096 * 1024 * 2);
  ushort* W1_b   = (ushort*)alloc((size_t)256 * 1024 * 2);
  ushort* W2_b   = (ushort*)alloc((size_t)128 * 256 * 2);
  ushort* W3_b   = (ushort*)alloc((size_t)256 * 128 * 2);
  float*  be     = (float*)alloc(4096 * 4);
  float*  bd     = (float*)alloc(4096 * 4);
  ushort* xe     = (ushort*)alloc((size_t)512 * 64 * 256 * 2);
  ushort* xd     = (ushort*)alloc((size_t)512 * 64 * 1024 * 2);
  ushort* hb     = (ushort*)alloc((size_t)2 * 64 * 1024 * 2);
  float*  cb     = (float*)alloc((size_t)64 * 1024 * 4);
  uint*   flagsE = (uint*)alloc(256 * 4);
  uint*   flagsD = (uint*)alloc(256 * 4);
  ushort* dhs    = (ushort*)alloc((size_t)512 * 64 * 1024 * 2);
  ushort* x1     = (ushort*)alloc((size_t)32768 * 256 * 2);
  ushort* x2     = (ushort*)alloc((size_t)32768 * 128 * 2);
  if (ws_size < off) return;  // constant branch per run; avoids corrupting memory

  auto cvt = [&](const float* s, ushort* d, size_t n) {
    int n4 = (int)(n / 4);
    k_cvt<<<(n4 + 255) / 256, 256, 0, stream>>>(s, d, n4);
  };
  cvt(eWih, eWih_b, (size_t)4096 * 256);
  cvt(eWhh, eWhh_b, (size_t)4096 * 1024);
  cvt(dWih, dWih_b, (size_t)4096 * 1024);
  cvt(dWhh, dWhh_b, (size_t)4096 * 1024);
  cvt(W1, W1_b, (size_t)256 * 1024);
  cvt(W2, W2_b, (size_t)128 * 256);
  cvt(W3, W3_b, (size_t)256 * 128);
  k_bias<<<16, 256, 0, stream>>>(eBih, eBhh, be, 4096);
  k_bias<<<16, 256, 0, stream>>>(dBih, dBhh, bd, 4096);
  k_xpose<<<64 * 512, 256, 0, stream>>>(in_seq, xe, 512, 256);
  k_xpose<<<64 * 512, 256, 0, stream>>>(tgt_seq, xd, 512, 1024);
  hipMemsetAsync(hb, 0, (size_t)2 * 64 * 1024 * 2, stream);
  hipMemsetAsync(cb, 0, (size_t)64 * 1024 * 4, stream);
  hipMemsetAsync(flagsE, 0, 256 * 4, stream);
  hipMemsetAsync(flagsD, 0, 256 * 4, stream);

  const unsigned ldsE = 16 * (256 + 1024) * 2 + 4 * 16 * 17 * 4 + 64 * 4 * 2;   // 45824
  const unsigned ldsD = 16 * (1024 + 1024) * 2 + 4 * 16 * 17 * 4 + 64 * 4 * 2;  // 70400
  hipFuncSetAttribute((const void*)k_lstm<256, false>, hipFuncAttributeMaxDynamicSharedMemorySize, (int)ldsE);
  hipFuncSetAttribute((const void*)k_lstm<1024, true>, hipFuncAttributeMaxDynamicSharedMemorySize, (int)ldsD);

  int T = 512;
  {
    const ushort* xp = xe; const ushort* wi = eWih_b; const ushort* wh = eWhh_b; const float* bp = be;
    ushort* hbp = hb; float* cbp = cb; ushort* hsp = nullptr; uint* flp = flagsE;
    void* args[] = {&xp, &wi, &wh, &bp, &hbp, &cbp, &hsp, &flp, &T};
    hipLaunchCooperativeKernel((const void*)k_lstm<256, false>, dim3(256), dim3(256), args, ldsE, stream);
  }
  {
    const ushort* xp = xd; const ushort* wi = dWih_b; const ushort* wh = dWhh_b; const float* bp = bd;
    ushort* hbp = hb; float* cbp = cb; ushort* hsp = dhs; uint* flp = flagsD;
    void* args[] = {&xp, &wi, &wh, &bp, &hbp, &cbp, &hsp, &flp, &T};
    hipLaunchCooperativeKernel((const void*)k_lstm<1024, true>, dim3(256), dim3(256), args, ldsD, stream);
  }

  k_gemm<true,  false><<<dim3(512, 4), 256, 0, stream>>>(dhs, W1_b, b1, x1, nullptr, 256, 1024);
  k_gemm<true,  false><<<dim3(512, 2), 256, 0, stream>>>(x1,  W2_b, b2, x2, nullptr, 128, 256);
  k_gemm<false, true ><<<dim3(512, 4), 256, 0, stream>>>(x2,  W3_b, b3, nullptr, (float*)d_out, 256, 128);
}